// Round 1
// baseline (418.873 us; speedup 1.0000x reference)
//
#include <hip/hip_runtime.h>
#include <hip/hip_bf16.h>

typedef unsigned short u16;
typedef __attribute__((ext_vector_type(4))) float f32x4;
typedef __attribute__((ext_vector_type(8))) __bf16 bf16x8;

#if __has_builtin(__builtin_amdgcn_exp2f)
#define EXP2(x) __builtin_amdgcn_exp2f(x)
#else
#define EXP2(x) exp2f(x)
#endif

#define LAM 20.60992915555662f   // log2(e)/0.07

// ---------------- Kernel 1: normalize embeddings, build hi/lo bf16 + transposed hi ----
__global__ __launch_bounds__(256) void k_emb_prep(
    const float* __restrict__ emb, float* __restrict__ emb_n,
    u16* __restrict__ ehi, u16* __restrict__ elo, u16* __restrict__ et,
    float* __restrict__ out) {
  int lane = threadIdx.x & 63;
  int e = blockIdx.x * 4 + (threadIdx.x >> 6);
  float x = emb[(size_t)e * 64 + lane];
  float ss = x * x;
#pragma unroll
  for (int mk = 1; mk < 64; mk <<= 1) ss += __shfl_xor(ss, mk);
  float inv = 1.0f / fmaxf(sqrtf(ss), 1e-12f);
  float n = x * inv;
  emb_n[(size_t)e * 64 + lane] = n;
  __bf16 h = (__bf16)n;
  __bf16 lo = (__bf16)(n - (float)h);
  ehi[(size_t)e * 64 + lane] = __builtin_bit_cast(u16, h);
  elo[(size_t)e * 64 + lane] = __builtin_bit_cast(u16, lo);
  et[(size_t)lane * 4096 + e] = __builtin_bit_cast(u16, h);
  if (blockIdx.x == 0 && threadIdx.x == 0) out[2097152] = 0.0f;  // entropy_loss
}

// ---------------- Kernel 2: transpose+normalize z, build fp32 + hi/lo bf16 -----------
__global__ __launch_bounds__(256) void k_z_prep(
    const float* __restrict__ z, float* __restrict__ zn,
    u16* __restrict__ zhi, u16* __restrict__ zlo) {
  __shared__ float zt[64][65];
  int tid = threadIdx.x;
  int p0 = blockIdx.x * 64;
  const float* zb = z + (size_t)(p0 >> 12) * 262144 + (p0 & 4095);
#pragma unroll
  for (int k = 0; k < 4; k++) {
    int idx = k * 1024 + tid * 4;
    int c = idx >> 6, px = idx & 63;
    float4 v = *reinterpret_cast<const float4*>(zb + (size_t)c * 4096 + px);
    zt[c][px] = v.x; zt[c][px + 1] = v.y; zt[c][px + 2] = v.z; zt[c][px + 3] = v.w;
  }
  __syncthreads();
  int px = tid >> 2, cq = tid & 3;
  float ss = 0.f;
#pragma unroll
  for (int j = 0; j < 16; j++) { float v = zt[cq * 16 + j][px]; ss += v * v; }
  ss += __shfl_xor(ss, 1);
  ss += __shfl_xor(ss, 2);
  float inv = 1.0f / fmaxf(sqrtf(ss), 1e-12f);
  int p = p0 + px;
#pragma unroll
  for (int j0 = 0; j0 < 16; j0 += 4) {
    float vv[4]; u16 hs[4], ls[4];
#pragma unroll
    for (int j = 0; j < 4; j++) {
      float n = zt[cq * 16 + j0 + j][px] * inv;
      vv[j] = n;
      __bf16 h = (__bf16)n;
      hs[j] = __builtin_bit_cast(u16, h);
      __bf16 l = (__bf16)(n - (float)h);
      ls[j] = __builtin_bit_cast(u16, l);
    }
    float4 o; o.x = vv[0]; o.y = vv[1]; o.z = vv[2]; o.w = vv[3];
    *reinterpret_cast<float4*>(zn + (size_t)p * 64 + cq * 16 + j0) = o;
    *reinterpret_cast<ushort4*>(zhi + (size_t)p * 64 + cq * 16 + j0) = make_ushort4(hs[0], hs[1], hs[2], hs[3]);
    *reinterpret_cast<ushort4*>(zlo + (size_t)p * 64 + cq * 16 + j0) = make_ushort4(ls[0], ls[1], ls[2], ls[3]);
  }
}

// ---------------- Kernel 3: fused softmax-VQ (flash-style, no online max needed) -----
#define UPD(r, val, idx)                                              \
  {                                                                   \
    float _v = (val); int _ix = (idx);                                \
    if (_v > v1[r]) { v2[r] = v1[r]; i2[r] = i1[r]; v1[r] = _v; i1[r] = _ix; } \
    else if (_v > v2[r]) { v2[r] = _v; i2[r] = _ix; }                 \
  }

__global__ __launch_bounds__(256) void k_main(
    const float* __restrict__ zn, const float* __restrict__ emb_n,
    const u16* __restrict__ zhi, const u16* __restrict__ zlo,
    const u16* __restrict__ ehi, const u16* __restrict__ elo,
    const u16* __restrict__ et, float* __restrict__ out) {
  __shared__ union {
    struct { u16 ehi[64][72]; u16 elo[64][72]; u16 et[64][72]; } s;  // 27648 B
    float olds[64][68];                                              // 17408 B
  } sm;
  __shared__ float p_l[4][16][68];  // per-wave P buffer

  const int tid = threadIdx.x;
  const int w = tid >> 6, lane = tid & 63, g = lane >> 4, c = lane & 15;
  const int p0 = blockIdx.x * 64;
  const int qg = p0 + w * 16 + c;  // A-frag row (pixel) for this lane

  // Q fragments (hi/lo), layout: lane holds row (lane&15), k = 8*(lane>>4)+j
  bf16x8 qhi[2], qlo[2];
#pragma unroll
  for (int kb = 0; kb < 2; kb++) {
    qhi[kb] = *reinterpret_cast<const bf16x8*>(zhi + (size_t)qg * 64 + kb * 32 + 8 * g);
    qlo[kb] = *reinterpret_cast<const bf16x8*>(zlo + (size_t)qg * 64 + kb * 32 + 8 * g);
  }

  f32x4 O[4];
#pragma unroll
  for (int dt = 0; dt < 4; dt++) O[dt] = (f32x4){0.f, 0.f, 0.f, 0.f};
  float v1[4], v2[4]; int i1[4], i2[4];
#pragma unroll
  for (int r = 0; r < 4; r++) { v1[r] = -1e30f; v2[r] = -1e30f; i1[r] = 0; i2[r] = 1; }

  for (int ch = 0; ch < 64; ch++) {
    int e0 = ch * 64;
    __syncthreads();  // previous chunk fully consumed
    // stage 64 embeddings: ehi/elo [e][d], et (V^T) [d][e]
#pragma unroll
    for (int u = 0; u < 2; u++) {
      int uu = tid + u * 256;
      int row = uu >> 3, seg = uu & 7;
      *reinterpret_cast<uint4*>(&sm.s.ehi[row][seg * 8]) =
          *reinterpret_cast<const uint4*>(ehi + (size_t)(e0 + row) * 64 + seg * 8);
      *reinterpret_cast<uint4*>(&sm.s.elo[row][seg * 8]) =
          *reinterpret_cast<const uint4*>(elo + (size_t)(e0 + row) * 64 + seg * 8);
      *reinterpret_cast<uint4*>(&sm.s.et[row][seg * 8]) =
          *reinterpret_cast<const uint4*>(et + (size_t)row * 4096 + e0 + seg * 8);
    }
    __syncthreads();

    // --- QK^T: 4 e-tiles of 16, hi*hi + hi*lo + lo*hi ---
    f32x4 sa[4];
#pragma unroll
    for (int i = 0; i < 4; i++) {
      f32x4 acc = (f32x4){0.f, 0.f, 0.f, 0.f};
#pragma unroll
      for (int kb = 0; kb < 2; kb++) {
        bf16x8 bh = *reinterpret_cast<const bf16x8*>(&sm.s.ehi[16 * i + c][32 * kb + 8 * g]);
        bf16x8 bl = *reinterpret_cast<const bf16x8*>(&sm.s.elo[16 * i + c][32 * kb + 8 * g]);
        acc = __builtin_amdgcn_mfma_f32_16x16x32_bf16(qhi[kb], bh, acc, 0, 0, 0);
        acc = __builtin_amdgcn_mfma_f32_16x16x32_bf16(qhi[kb], bl, acc, 0, 0, 0);
        acc = __builtin_amdgcn_mfma_f32_16x16x32_bf16(qlo[kb], bh, acc, 0, 0, 0);
      }
      sa[i] = acc;
    }

    // --- p = exp2(LAM*S - LAM)  (cos<=1 bound; denominator cancels in l2norm) ---
#pragma unroll
    for (int i = 0; i < 4; i++) {
#pragma unroll
      for (int r = 0; r < 4; r++) {
        float sv = sa[i][r];
        UPD(r, sv, e0 + 16 * i + c);
        float pe = EXP2(fmaf(sv, LAM, -LAM));
        p_l[w][4 * g + r][16 * i + c] = pe;  // row q=(lane>>4)*4+r, col e
      }
    }

    // --- re-layout P: C-frag -> A-frag via per-wave LDS (lgkmcnt handled by compiler)
    bf16x8 pa[2];
#pragma unroll
    for (int h = 0; h < 2; h++) {
      float tmp[8];
      *reinterpret_cast<float4*>(tmp) =
          *reinterpret_cast<const float4*>(&p_l[w][c][32 * h + 8 * g]);
      *reinterpret_cast<float4*>(tmp + 4) =
          *reinterpret_cast<const float4*>(&p_l[w][c][32 * h + 8 * g + 4]);
      bf16x8 x;
#pragma unroll
      for (int j = 0; j < 8; j++) x[j] = (__bf16)tmp[j];
      pa[h] = x;
    }

    // --- PV: O[16q x 64d] += P[16 x 64e] * V[64e x 64d] ---
#pragma unroll
    for (int dt = 0; dt < 4; dt++) {
#pragma unroll
      for (int h = 0; h < 2; h++) {
        bf16x8 vb = *reinterpret_cast<const bf16x8*>(&sm.s.et[16 * dt + c][32 * h + 8 * g]);
        O[dt] = __builtin_amdgcn_mfma_f32_16x16x32_bf16(pa[h], vb, O[dt], 0, 0, 0);
      }
    }
  }

  __syncthreads();  // all waves done with staged chunks; sm reusable as olds

  // --- l2norm rows of O, write to transpose buffer ---
#pragma unroll
  for (int r = 0; r < 4; r++) {
    float ss = 0.f;
#pragma unroll
    for (int dt = 0; dt < 4; dt++) ss += O[dt][r] * O[dt][r];
#pragma unroll
    for (int mk = 1; mk < 16; mk <<= 1) ss += __shfl_xor(ss, mk);
    float inv = 1.0f / fmaxf(sqrtf(ss), 1e-30f);
    int ql = w * 16 + 4 * g + r;
#pragma unroll
    for (int dt = 0; dt < 4; dt++) sm.olds[ql][16 * dt + c] = O[dt][r] * inv;
  }

  // --- merge top-2 across the 16 lanes holding each row ---
#pragma unroll
  for (int r = 0; r < 4; r++) {
#pragma unroll
    for (int mk = 1; mk < 16; mk <<= 1) {
      float ov1 = __shfl_xor(v1[r], mk); int oi1 = __shfl_xor(i1[r], mk);
      float ov2 = __shfl_xor(v2[r], mk); int oi2 = __shfl_xor(i2[r], mk);
      if (ov1 > v1[r]) { v2[r] = v1[r]; i2[r] = i1[r]; v1[r] = ov1; i1[r] = oi1; }
      else if (ov1 > v2[r]) { v2[r] = ov1; i2[r] = oi1; }
      if (ov2 > v1[r]) { v2[r] = v1[r]; i2[r] = i1[r]; v1[r] = ov2; i1[r] = oi2; }
      else if (ov2 > v2[r]) { v2[r] = ov2; i2[r] = oi2; }
    }
  }
  // --- fp64 tiebreak of the two candidates against fp32 normalized data ---
  if (c == 0) {
#pragma unroll 1
    for (int r = 0; r < 4; r++) {
      int q = p0 + w * 16 + 4 * g + r;
      const float* zr = zn + (size_t)q * 64;
      const float* ea = emb_n + (size_t)i1[r] * 64;
      const float* eb = emb_n + (size_t)i2[r] * 64;
      double d1 = 0.0, d2 = 0.0;
      for (int k = 0; k < 64; k++) {
        d1 += (double)zr[k] * (double)ea[k];
        d2 += (double)zr[k] * (double)eb[k];
      }
      int best = i1[r];
      if (d2 > d1 || (d2 == d1 && i2[r] < i1[r])) best = i2[r];
      out[2097153 + q] = (float)best;  // indices chunk, stored as fp32 values
    }
  }

  __syncthreads();
  // --- coalesced transposed store of z_q to [b, c, h, w] ---
  {
    int cc = tid >> 2, part = tid & 3;
    size_t base = (size_t)(p0 >> 12) * 262144 + (size_t)cc * 4096 + (p0 & 4095) + part * 16;
#pragma unroll
    for (int j0 = 0; j0 < 16; j0 += 4) {
      float4 v;
      v.x = sm.olds[part * 16 + j0 + 0][cc];
      v.y = sm.olds[part * 16 + j0 + 1][cc];
      v.z = sm.olds[part * 16 + j0 + 2][cc];
      v.w = sm.olds[part * 16 + j0 + 3][cc];
      *reinterpret_cast<float4*>(out + base + j0) = v;
    }
  }
}

extern "C" void kernel_launch(void* const* d_in, const int* in_sizes, int n_in,
                              void* d_out, int out_size, void* d_ws, size_t ws_size,
                              hipStream_t stream) {
  const float* z = (const float*)d_in[0];
  const float* emb = (const float*)d_in[1];
  float* out = (float*)d_out;
  char* ws = (char*)d_ws;
  // workspace layout (bytes)
  float* zn   = (float*)(ws + 0);         // 32768*64*4  = 8388608
  float* embn = (float*)(ws + 8388608);   // 4096*64*4   = 1048576
  u16* zhi = (u16*)(ws + 9437184);        // 32768*64*2  = 4194304
  u16* zlo = (u16*)(ws + 13631488);       // 4194304
  u16* ehi = (u16*)(ws + 17825792);       // 4096*64*2   = 524288
  u16* elo = (u16*)(ws + 18350080);       // 524288
  u16* et  = (u16*)(ws + 18874368);       // 524288  (total 19398656 B)

  k_emb_prep<<<dim3(1024), dim3(256), 0, stream>>>(emb, embn, ehi, elo, et, out);
  k_z_prep<<<dim3(512), dim3(256), 0, stream>>>(z, zn, zhi, zlo);
  k_main<<<dim3(512), dim3(256), 0, stream>>>(zn, embn, zhi, zlo, ehi, elo, et, out);
}

// Round 2
// 313.026 us; speedup vs baseline: 1.3381x; 1.3381x over previous
//
#include <hip/hip_runtime.h>
#include <hip/hip_bf16.h>

typedef unsigned short u16;
typedef unsigned int u32;
typedef __attribute__((ext_vector_type(4))) float f32x4;
typedef __attribute__((ext_vector_type(8))) __bf16 bf16x8;

#if __has_builtin(__builtin_amdgcn_exp2f)
#define EXP2(x) __builtin_amdgcn_exp2f(x)
#else
#define EXP2(x) exp2f(x)
#endif

#define LAM 20.60992915555662f   // log2(e)/0.07

__device__ __forceinline__ void gl16(const void* g, void* l) {
  __builtin_amdgcn_global_load_lds(
      (const __attribute__((address_space(1))) unsigned int*)g,
      (__attribute__((address_space(3))) unsigned int*)l, 16, 0, 0);
}

// ---------------- Kernel 1: normalize embeddings -> swizzled ehi/elo/et + einv ------
// one block per 64-embedding chunk
__global__ __launch_bounds__(256) void k_emb_prep(
    const float* __restrict__ emb, float* __restrict__ einv,
    u16* __restrict__ ehi, u16* __restrict__ elo, u16* __restrict__ et,
    float* __restrict__ out) {
  __shared__ u16 ehl[64][72];
  const int ch = blockIdx.x, t = threadIdx.x;
  const int e = t >> 2, q = t & 3;
  const int ge = ch * 64 + e;
  float v[16];
#pragma unroll
  for (int b = 0; b < 4; b++)
    *reinterpret_cast<float4*>(v + 4 * b) =
        *reinterpret_cast<const float4*>(emb + (size_t)ge * 64 + q * 16 + 4 * b);
  float ss = 0.f;
#pragma unroll
  for (int j = 0; j < 16; j++) ss += v[j] * v[j];
  ss += __shfl_xor(ss, 1);
  ss += __shfl_xor(ss, 2);
  float inv = 1.0f / fmaxf(sqrtf(ss), 1e-12f);
  if (q == 0) einv[ge] = inv;
  u16 hi[16], lo[16];
#pragma unroll
  for (int j = 0; j < 16; j++) {
    float n = v[j] * inv;
    __bf16 h = (__bf16)n;
    hi[j] = __builtin_bit_cast(u16, h);
    __bf16 l = (__bf16)(n - (float)h);
    lo[j] = __builtin_bit_cast(u16, l);
  }
  // global swizzled hi/lo writes (16B blocks permuted within the 128B row)
#pragma unroll
  for (int bb = 0; bb < 2; bb++) {
    int b = 2 * q + bb;
    int pos = (b ^ (e & 7)) * 8;
    *reinterpret_cast<uint4*>(ehi + (size_t)ge * 64 + pos) =
        *reinterpret_cast<const uint4*>(hi + 8 * bb);
    *reinterpret_cast<uint4*>(elo + (size_t)ge * 64 + pos) =
        *reinterpret_cast<const uint4*>(lo + 8 * bb);
  }
  // LDS copy for transpose
  *reinterpret_cast<uint4*>(&ehl[e][q * 16]) = *reinterpret_cast<const uint4*>(hi);
  *reinterpret_cast<uint4*>(&ehl[e][q * 16 + 8]) = *reinterpret_cast<const uint4*>(hi + 8);
  __syncthreads();
  // phase 2: et[d][e] swizzled
  {
    const int d = t >> 2, eq = t & 3;
    u16 vals[16];
#pragma unroll
    for (int j = 0; j < 16; j++) vals[j] = ehl[eq * 16 + j][d];
#pragma unroll
    for (int bb = 0; bb < 2; bb++) {
      int b = 2 * eq + bb;
      int pos = (b ^ (d & 7)) * 8;
      *reinterpret_cast<uint4*>(et + (size_t)ch * 4096 + d * 64 + pos) =
          *reinterpret_cast<const uint4*>(vals + 8 * bb);
    }
  }
  if (ch == 0 && t == 0) out[2097152] = 0.0f;  // entropy_loss
}

// ---------------- Kernel 2: transpose+normalize z -> hi/lo bf16 ----------------------
__global__ __launch_bounds__(256) void k_z_prep(
    const float* __restrict__ z, u16* __restrict__ zhi, u16* __restrict__ zlo) {
  __shared__ float zt[64][65];
  int tid = threadIdx.x;
  int p0 = blockIdx.x * 64;
  const float* zb = z + (size_t)(p0 >> 12) * 262144 + (p0 & 4095);
#pragma unroll
  for (int k = 0; k < 4; k++) {
    int idx = k * 1024 + tid * 4;
    int c = idx >> 6, px = idx & 63;
    float4 v = *reinterpret_cast<const float4*>(zb + (size_t)c * 4096 + px);
    zt[c][px] = v.x; zt[c][px + 1] = v.y; zt[c][px + 2] = v.z; zt[c][px + 3] = v.w;
  }
  __syncthreads();
  int px = tid >> 2, cq = tid & 3;
  float ss = 0.f;
#pragma unroll
  for (int j = 0; j < 16; j++) { float v = zt[cq * 16 + j][px]; ss += v * v; }
  ss += __shfl_xor(ss, 1);
  ss += __shfl_xor(ss, 2);
  float inv = 1.0f / fmaxf(sqrtf(ss), 1e-12f);
  int p = p0 + px;
#pragma unroll
  for (int j0 = 0; j0 < 16; j0 += 4) {
    u16 hs[4], ls[4];
#pragma unroll
    for (int j = 0; j < 4; j++) {
      float n = zt[cq * 16 + j0 + j][px] * inv;
      __bf16 h = (__bf16)n;
      hs[j] = __builtin_bit_cast(u16, h);
      __bf16 l = (__bf16)(n - (float)h);
      ls[j] = __builtin_bit_cast(u16, l);
    }
    *reinterpret_cast<ushort4*>(zhi + (size_t)p * 64 + cq * 16 + j0) = make_ushort4(hs[0], hs[1], hs[2], hs[3]);
    *reinterpret_cast<ushort4*>(zlo + (size_t)p * 64 + cq * 16 + j0) = make_ushort4(ls[0], ls[1], ls[2], ls[3]);
  }
}

// ---------------- Kernel 3: fused softmax-VQ main (e-split halves) -------------------
#define UPD(r, val, idx)                                              \
  {                                                                   \
    float _v = (val); int _ix = (idx);                                \
    if (_v > v1[r]) { v2[r] = v1[r]; i2[r] = i1[r]; v1[r] = _v; i1[r] = _ix; } \
    else if (_v > v2[r]) { v2[r] = _v; i2[r] = _ix; }                 \
  }

__global__ __launch_bounds__(256, 5) void k_main(
    const u16* __restrict__ zhi, const u16* __restrict__ zlo,
    const u16* __restrict__ ehi, const u16* __restrict__ elo,
    const u16* __restrict__ et, float* __restrict__ Osum,
    float* __restrict__ tv1, float* __restrict__ tv2, u32* __restrict__ tix) {
  __shared__ __align__(16) u16 s_ehi[4096];   // [64 e][64 d] swizzled
  __shared__ __align__(16) u16 s_elo[4096];
  __shared__ __align__(16) u16 s_et[4096];    // [64 d][64 e] swizzled
  __shared__ __align__(16) u16 s_p[4][1024];  // per-wave [16 q][64 e] swizzled bf16

  const int t = threadIdx.x;
  const int w = t >> 6, lane = t & 63, g = lane >> 4, c = lane & 15;
  const int bx = blockIdx.x;
  const int px0 = (bx >> 1) * 64;
  const int s = bx & 1;
  const int qg = px0 + w * 16 + c;

  // per-lane swizzled 16B-block column offsets (u16 units), key = 8*(row&7) with row=c
  const int x0 = 8 * ((0 + g) ^ (c & 7));
  const int x1 = 8 * ((4 + g) ^ (c & 7));

  bf16x8 qhi[2], qlo[2];
#pragma unroll
  for (int kb = 0; kb < 2; kb++) {
    qhi[kb] = *reinterpret_cast<const bf16x8*>(zhi + (size_t)qg * 64 + kb * 32 + 8 * g);
    qlo[kb] = *reinterpret_cast<const bf16x8*>(zlo + (size_t)qg * 64 + kb * 32 + 8 * g);
  }

  f32x4 O[4];
#pragma unroll
  for (int dt = 0; dt < 4; dt++) O[dt] = (f32x4){0.f, 0.f, 0.f, 0.f};
  float v1[4], v2[4]; int i1[4], i2[4];
#pragma unroll
  for (int r = 0; r < 4; r++) { v1[r] = -1e30f; v2[r] = -1e30f; i1[r] = 0; i2[r] = 1; }

  for (int ch = 0; ch < 32; ch++) {
    const int chg = s * 32 + ch;
    __syncthreads();  // previous chunk fully consumed
    {
      const u16* eh = ehi + (size_t)chg * 4096;
      const u16* el = elo + (size_t)chg * 4096;
      const u16* ev = et + (size_t)chg * 4096;
      gl16(eh + t * 8, s_ehi + t * 8);
      gl16(eh + 2048 + t * 8, s_ehi + 2048 + t * 8);
      gl16(el + t * 8, s_elo + t * 8);
      gl16(el + 2048 + t * 8, s_elo + 2048 + t * 8);
      gl16(ev + t * 8, s_et + t * 8);
      gl16(ev + 2048 + t * 8, s_et + 2048 + t * 8);
    }
    __syncthreads();  // staging complete (vmcnt drained by barrier)

    // --- QK^T: hi*hi + hi*lo + lo*hi ---
    f32x4 sa[4];
#pragma unroll
    for (int i = 0; i < 4; i++) {
      f32x4 acc = (f32x4){0.f, 0.f, 0.f, 0.f};
#pragma unroll
      for (int kb = 0; kb < 2; kb++) {
        int col = kb ? x1 : x0;
        bf16x8 bh = *reinterpret_cast<const bf16x8*>(&s_ehi[i * 1024 + c * 64 + col]);
        bf16x8 bl = *reinterpret_cast<const bf16x8*>(&s_elo[i * 1024 + c * 64 + col]);
        acc = __builtin_amdgcn_mfma_f32_16x16x32_bf16(qhi[kb], bh, acc, 0, 0, 0);
        acc = __builtin_amdgcn_mfma_f32_16x16x32_bf16(qhi[kb], bl, acc, 0, 0, 0);
        acc = __builtin_amdgcn_mfma_f32_16x16x32_bf16(qlo[kb], bh, acc, 0, 0, 0);
      }
      sa[i] = acc;
    }

    // --- p = exp2(LAM*S - LAM), top-2 track, store p (bf16, swizzled) ---
    const int e0 = chg * 64;
#pragma unroll
    for (int i = 0; i < 4; i++) {
#pragma unroll
      for (int r = 0; r < 4; r++) {
        float sv = sa[i][r];
        UPD(r, sv, e0 + 16 * i + c);
        __bf16 pb = (__bf16)EXP2(fmaf(sv, LAM, -LAM));
        int key = 32 * (g & 1) + 8 * r;  // = 8*((4g+r)&7)
        s_p[w][(4 * g + r) * 64 + ((16 * i + c) ^ key)] = __builtin_bit_cast(u16, pb);
      }
    }

    // --- PV: O[16q x 64d] += P[16 x 64e] * V[64e x 64d] ---
    bf16x8 pa[2];
    pa[0] = *reinterpret_cast<const bf16x8*>(&s_p[w][c * 64 + x0]);
    pa[1] = *reinterpret_cast<const bf16x8*>(&s_p[w][c * 64 + x1]);
#pragma unroll
    for (int dt = 0; dt < 4; dt++) {
#pragma unroll
      for (int h = 0; h < 2; h++) {
        bf16x8 vb = *reinterpret_cast<const bf16x8*>(&s_et[dt * 1024 + c * 64 + (h ? x1 : x0)]);
        O[dt] = __builtin_amdgcn_mfma_f32_16x16x32_bf16(pa[h], vb, O[dt], 0, 0, 0);
      }
    }
  }

  // --- merge top-2 across the 16 c-lanes of each row group ---
#pragma unroll
  for (int r = 0; r < 4; r++) {
#pragma unroll
    for (int mk = 1; mk < 16; mk <<= 1) {
      float ov1 = __shfl_xor(v1[r], mk); int oi1 = __shfl_xor(i1[r], mk);
      float ov2 = __shfl_xor(v2[r], mk); int oi2 = __shfl_xor(i2[r], mk);
      if (ov1 > v1[r]) { v2[r] = v1[r]; i2[r] = i1[r]; v1[r] = ov1; i1[r] = oi1; }
      else if (ov1 > v2[r]) { v2[r] = ov1; i2[r] = oi1; }
      if (ov2 > v2[r]) { v2[r] = ov2; i2[r] = oi2; }
    }
  }
  if (c == 0) {
#pragma unroll
    for (int r = 0; r < 4; r++) {
      int px = px0 + w * 16 + 4 * g + r;
      int o = s * 32768 + px;
      tv1[o] = v1[r];
      tv2[o] = v2[r];
      tix[o] = ((u32)i1[r] << 12) | (u32)i2[r];
    }
  }
  // --- partial O accumulate (both halves atomically add) ---
#pragma unroll
  for (int dt = 0; dt < 4; dt++) {
#pragma unroll
    for (int r = 0; r < 4; r++) {
      int px = px0 + w * 16 + 4 * g + r;
      unsafeAtomicAdd(&Osum[(size_t)px * 64 + dt * 16 + c], O[dt][r]);
    }
  }
}

// ---------------- Kernel 4: combine halves, l2norm, transpose-store, argmax ----------
__global__ __launch_bounds__(256) void k_combine(
    const float* __restrict__ Osum, const float* __restrict__ tv1,
    const float* __restrict__ tv2, const u32* __restrict__ tix,
    const float* __restrict__ z, const float* __restrict__ emb,
    const float* __restrict__ einv, float* __restrict__ out) {
  __shared__ float olds[64][68];
  const int t = threadIdx.x;
  const int px0 = blockIdx.x * 64;
  const int pl = t >> 2, part = t & 3;
  const int px = px0 + pl;

  float v[16];
  const float* ob = Osum + (size_t)px * 64 + part * 16;
#pragma unroll
  for (int b = 0; b < 4; b++) *reinterpret_cast<float4*>(v + 4 * b) = *reinterpret_cast<const float4*>(ob + 4 * b);
  float ss = 0.f;
#pragma unroll
  for (int j = 0; j < 16; j++) ss += v[j] * v[j];
  ss += __shfl_xor(ss, 1);
  ss += __shfl_xor(ss, 2);
  float inv = 1.0f / fmaxf(sqrtf(ss), 1e-30f);
#pragma unroll
  for (int b = 0; b < 4; b++) {
    float4 o;
    o.x = v[4 * b] * inv; o.y = v[4 * b + 1] * inv; o.z = v[4 * b + 2] * inv; o.w = v[4 * b + 3] * inv;
    *reinterpret_cast<float4*>(&olds[pl][part * 16 + 4 * b]) = o;
  }

  // top-2 merge across halves
  float m1 = tv1[px], m2 = tv2[px];
  u32 ia = tix[px];
  int j1 = (int)(ia >> 12), j2 = (int)(ia & 0xFFF);
  {
    float b1 = tv1[32768 + px], b2 = tv2[32768 + px];
    u32 ib = tix[32768 + px];
    int k1 = (int)(ib >> 12), k2 = (int)(ib & 0xFFF);
    if (b1 > m1) { m2 = m1; j2 = j1; m1 = b1; j1 = k1; }
    else if (b1 > m2) { m2 = b1; j2 = k1; }
    if (b2 > m2) { m2 = b2; j2 = k2; }
  }
  // fp64 recompute of the two candidates (scale of z irrelevant to the compare)
  {
    const int b_ = px >> 12, hw = px & 4095;
    const float* zc = z + (size_t)b_ * 262144 + hw;
    const float* e1 = emb + (size_t)j1 * 64;
    const float* e2 = emb + (size_t)j2 * 64;
    double d1 = 0.0, d2 = 0.0;
#pragma unroll
    for (int j = 0; j < 16; j++) {
      int cc = part * 16 + j;
      double zv = (double)zc[(size_t)cc * 4096];
      d1 += zv * (double)e1[cc];
      d2 += zv * (double)e2[cc];
    }
    d1 += __shfl_xor(d1, 1); d1 += __shfl_xor(d1, 2);
    d2 += __shfl_xor(d2, 1); d2 += __shfl_xor(d2, 2);
    d1 *= (double)einv[j1];
    d2 *= (double)einv[j2];
    if (part == 0) {
      int best = (d2 > d1 || (d2 == d1 && j2 < j1)) ? j2 : j1;
      out[2097153 + px] = (float)best;
    }
  }

  __syncthreads();
  // coalesced transposed store of z_q to [b, c, h, w]
  {
    int cc = t >> 2, pp = t & 3;
    size_t base = (size_t)(px0 >> 12) * 262144 + (size_t)cc * 4096 + (px0 & 4095) + pp * 16;
#pragma unroll
    for (int j0 = 0; j0 < 16; j0 += 4) {
      float4 o;
      o.x = olds[pp * 16 + j0 + 0][cc];
      o.y = olds[pp * 16 + j0 + 1][cc];
      o.z = olds[pp * 16 + j0 + 2][cc];
      o.w = olds[pp * 16 + j0 + 3][cc];
      *reinterpret_cast<float4*>(out + base + j0) = o;
    }
  }
}

extern "C" void kernel_launch(void* const* d_in, const int* in_sizes, int n_in,
                              void* d_out, int out_size, void* d_ws, size_t ws_size,
                              hipStream_t stream) {
  const float* z = (const float*)d_in[0];
  const float* emb = (const float*)d_in[1];
  float* out = (float*)d_out;
  char* ws = (char*)d_ws;
  // workspace layout (bytes), total 19152896
  float* Osum = (float*)(ws + 0);          // 32768*64*4 = 8388608
  float* tv1  = (float*)(ws + 8388608);    // 2*32768*4 = 262144
  float* tv2  = (float*)(ws + 8650752);    // 262144
  u32*   tix  = (u32*)(ws + 8912896);      // 262144
  u16*   zhi  = (u16*)(ws + 9175040);      // 4194304
  u16*   zlo  = (u16*)(ws + 13369344);     // 4194304
  u16*   ehi  = (u16*)(ws + 17563648);     // 524288
  u16*   elo  = (u16*)(ws + 18087936);     // 524288
  u16*   et   = (u16*)(ws + 18612224);     // 524288
  float* einv = (float*)(ws + 19136512);   // 16384

  hipMemsetAsync(Osum, 0, 8388608, stream);
  k_emb_prep<<<dim3(64), dim3(256), 0, stream>>>(emb, einv, ehi, elo, et, out);
  k_z_prep<<<dim3(512), dim3(256), 0, stream>>>(z, zhi, zlo);
  k_main<<<dim3(1024), dim3(256), 0, stream>>>(zhi, zlo, ehi, elo, et, Osum, tv1, tv2, tix);
  k_combine<<<dim3(512), dim3(256), 0, stream>>>(Osum, tv1, tv2, tix, z, emb, einv, out);
}